// Round 5
// baseline (329.784 us; speedup 1.0000x reference)
//
#include <hip/hip_runtime.h>
#include <hip/hip_bf16.h>
#include <stdint.h>

// ---------------------------------------------------------------------------
// SparseLinear: y[B,N] = x[B,M] @ W^T + bias, W given as CSR.
// R8b: identical to R8 (resubmit -- previous bench died with an MI355X
// container infra error, no kernel verdict). Audit found no hang/fault
// mechanism: barriers are wave-uniform (1/ktile), all addresses in-bounds,
// waitcnt imm valid, no graph-capture violations.
//
// R8 rationale (from R7 post-mortem): phase = 1341 cyc = MFMA 621 + LDS
// ~700, ADDITIVE -- the 2-barriers-per-phase lockstep put ds_reads and MFMA
// in disjoint segments. Within a K-tile all operands are published at the
// tile-head barrier, so per-phase barriers were pure over-synchronization.
// New tile structure (64 tiles, 1 barrier each):
//   vmcnt(0)           // this tile's stages landed (issued a FULL tile ago)
//   s_barrier          // publish cur buffers; WAR-gate for nxt staging
//   reads step0 ; issue 8 stage loads (tile t+1 into other buf)
//   reads step1 ; MFMA step0 ; reads step2 ; MFMA step1 ; reads step3 ;
//   MFMA step2 ; MFMA step3    // reg-pipelined: LDS runs under MFMA
// Steps = (MA,KS): (0,k0),(1,k0),(0,k1),(1,k1); per-accumulator order still
// k0-then-k1 -> bit-identical results. Named frag sets (rule #20).
// WAR proof: a wave's reads of buf complete before its MFMAs (operand dep),
// MFMAs precede the next head barrier, stages into that buf issue after it.
// RAW proof: vmcnt(0) retires own stages; barrier publishes all waves'.
// ---------------------------------------------------------------------------

#define B_DIM 4096
#define M_DIM 4096
#define N_DIM 4096
#define NNZ_ROW 819

typedef __attribute__((ext_vector_type(8))) __bf16 bf16x8;
typedef __attribute__((ext_vector_type(4))) float f32x4;

__device__ __forceinline__ unsigned short f32_to_bf16(float f) {
    union { float f; unsigned int u; } v;
    v.f = f;
    unsigned int r = v.u + 0x7FFFu + ((v.u >> 16) & 1u);  // RNE
    return (unsigned short)(r >> 16);
}

__device__ __forceinline__ void load_lds16(const void* g, void* l) {
    __builtin_amdgcn_global_load_lds(
        (const __attribute__((address_space(1))) void*)g,
        (__attribute__((address_space(3))) void*)l,
        16, 0, 0);
}

// ---- merged prologue: densify W rows (blocks 0..4095) + X fp32->bf16
//      (blocks 4096..12287, 8 floats/thread, exact grid) --------------------
__global__ __launch_bounds__(256) void prep(
    const float* __restrict__ wval,
    const int* __restrict__ cols,
    unsigned short* __restrict__ wb,
    const float4* __restrict__ x,
    uint4* __restrict__ xb) {
    const int tid = threadIdx.x;
    if (blockIdx.x >= N_DIM) {
        const int i = (blockIdx.x - N_DIM) * 256 + tid;   // 0 .. 2M-1, exact
        const float4 a = x[2 * i];
        const float4 b = x[2 * i + 1];
        union { ushort ush[8]; uint4 u4; } o;
        o.ush[0] = f32_to_bf16(a.x); o.ush[1] = f32_to_bf16(a.y);
        o.ush[2] = f32_to_bf16(a.z); o.ush[3] = f32_to_bf16(a.w);
        o.ush[4] = f32_to_bf16(b.x); o.ush[5] = f32_to_bf16(b.y);
        o.ush[6] = f32_to_bf16(b.z); o.ush[7] = f32_to_bf16(b.w);
        xb[i] = o.u4;
        return;
    }
    __shared__ __attribute__((aligned(16))) unsigned short row_s[M_DIM];  // 8 KB
    const int row = blockIdx.x;
    uint4* rs4 = (uint4*)row_s;
    rs4[tid]       = make_uint4(0u, 0u, 0u, 0u);
    rs4[tid + 256] = make_uint4(0u, 0u, 0u, 0u);
    __syncthreads();
    const size_t base = (size_t)row * NNZ_ROW;
    for (int j = tid; j < NNZ_ROW; j += 256) {
        const int c = cols[base + j];
        row_s[c] = f32_to_bf16(wval[base + j]);
    }
    __syncthreads();
    uint4* dst = (uint4*)(wb + (size_t)row * M_DIM);
    dst[tid]       = rs4[tid];
    dst[tid + 256] = rs4[tid + 256];
}

// ---------------------------------------------------------------------------
// Stage one 128-row half-tile (128 rows x 64 k, bf16) for K-offset kt.
// LDS dest LINEAR: wave w covers segments {2w,2w+1}; lane's 16B slot is
// (row r = seg*8 + (l>>3), chunk' = l&7); LDS(r,c') holds global chunk
// c' ^ (r&7) = (l&7) ^ (l>>3).
// ---------------------------------------------------------------------------
__device__ __forceinline__ void stage_half(
    const unsigned short* __restrict__ src,
    int grow0, int kt, unsigned short* dst, int w, int l) {
#pragma unroll
    for (int j = 0; j < 2; ++j) {
        const int seg = w * 2 + j;
        const int r   = seg * 8 + (l >> 3);
        const int cg  = (l >> 3) ^ (l & 7);
        load_lds16(src + (size_t)(grow0 + r) * M_DIM + kt + cg * 8,
                   dst + seg * 512);
    }
}

#define MFMA_STEP(MA, ASET, BSET)                                              \
    __builtin_amdgcn_s_setprio(1);                                             \
    _Pragma("unroll")                                                          \
    for (int mf = 0; mf < 4; ++mf)                                             \
        _Pragma("unroll")                                                      \
        for (int nb = 0; nb < 2; ++nb)                                         \
            _Pragma("unroll")                                                  \
            for (int nf = 0; nf < 2; ++nf)                                     \
                acc[MA][mf][nb][nf] =                                          \
                    __builtin_amdgcn_mfma_f32_16x16x32_bf16(                   \
                        ASET[mf], BSET[nb][nf], acc[MA][mf][nb][nf], 0, 0, 0); \
    __builtin_amdgcn_s_setprio(0);

// ---------------------------------------------------------------------------
// One K-tile: 4 (MA,KS) steps, register-pipelined, single head barrier.
// Fragment addressing (proven R7): row = quad + mf*16 + l15, chunk
// c = KS*4 + (l>>4), stored at chunk' = c ^ (row&7) = c ^ (l&7).
// ---------------------------------------------------------------------------
__device__ __forceinline__ void ktile(
    const unsigned short* As_c, const unsigned short* Bs_c,
    unsigned short* As_n, unsigned short* Bs_n,
    const unsigned short* __restrict__ Xb, const unsigned short* __restrict__ Wb,
    int bm0, int bn0, int knext, bool do_stage,
    int wr, int wc, int w, int l, f32x4 (&acc)[2][4][2][2])
{
    __builtin_amdgcn_s_waitcnt(0x0F70);   // vmcnt(0): this tile's stages landed
    __builtin_amdgcn_s_barrier();         // publish cur; WAR-gate nxt staging

    const int l15 = l & 15;
    const int lg  = l >> 4;
    const int lx  = l & 7;
    const int ck0 = (lg ^ lx) << 3;          // KS=0 ushort offset within row
    const int ck1 = ((4 + lg) ^ lx) << 3;    // KS=1

    const unsigned short* A0 = As_c + (wr * 64 + l15) * 64;          // MA=0
    const unsigned short* A1 = A0 + 128 * 64;                        // MA=1
    const unsigned short* B0 = Bs_c + (wc * 32 + l15) * 64;          // nb=0
    const unsigned short* B1 = B0 + 128 * 64;                        // nb=1

    bf16x8 a0k0[4], a1k0[4], a0k1[4], a1k1[4], bk0[2][2], bk1[2][2];

    // step-0 operands (consumed first)
#pragma unroll
    for (int mf = 0; mf < 4; ++mf)
        a0k0[mf] = *(const bf16x8*)(A0 + mf * 1024 + ck0);
#pragma unroll
    for (int nf = 0; nf < 2; ++nf) {
        bk0[0][nf] = *(const bf16x8*)(B0 + nf * 1024 + ck0);
        bk0[1][nf] = *(const bf16x8*)(B1 + nf * 1024 + ck0);
    }
    // stage next tile's buffers (retired by the NEXT tile's vmcnt(0):
    // ~one full K-tile of slack)
    if (do_stage) {
        stage_half(Xb, bm0,       knext, As_n,        w, l);
        stage_half(Wb, bn0,       knext, Bs_n,        w, l);
        stage_half(Xb, bm0 + 128, knext, As_n + 8192, w, l);
        stage_half(Wb, bn0 + 128, knext, Bs_n + 8192, w, l);
    }
    // read-ahead step1, then MFMA step0 (reads run under the MFMA cluster)
#pragma unroll
    for (int mf = 0; mf < 4; ++mf)
        a1k0[mf] = *(const bf16x8*)(A1 + mf * 1024 + ck0);

    MFMA_STEP(0, a0k0, bk0)

    // read-ahead step2
#pragma unroll
    for (int mf = 0; mf < 4; ++mf)
        a0k1[mf] = *(const bf16x8*)(A0 + mf * 1024 + ck1);
#pragma unroll
    for (int nf = 0; nf < 2; ++nf) {
        bk1[0][nf] = *(const bf16x8*)(B0 + nf * 1024 + ck1);
        bk1[1][nf] = *(const bf16x8*)(B1 + nf * 1024 + ck1);
    }

    MFMA_STEP(1, a1k0, bk0)

    // read-ahead step3
#pragma unroll
    for (int mf = 0; mf < 4; ++mf)
        a1k1[mf] = *(const bf16x8*)(A1 + mf * 1024 + ck1);

    MFMA_STEP(0, a0k1, bk1)
    MFMA_STEP(1, a1k1, bk1)
}

// ---- main GEMM: C[b,n] = sum_k Xb[b,k]*Wb[n,k] + bias[n] -------------------
__global__ __launch_bounds__(512, 2) void gemm_bt_bias(
    const unsigned short* __restrict__ Xb,   // [B][M] bf16 bits
    const unsigned short* __restrict__ Wb,   // [N][M] bf16 bits
    const float* __restrict__ bias,          // [N]
    float* __restrict__ out)                 // [B][N]
{
    __shared__ __attribute__((aligned(16))) unsigned short As0[16384];
    __shared__ __attribute__((aligned(16))) unsigned short Bs0[16384];
    __shared__ __attribute__((aligned(16))) unsigned short As1[16384];
    __shared__ __attribute__((aligned(16))) unsigned short Bs1[16384];

    const int tid = threadIdx.x;
    const int w   = tid >> 6;     // wave 0..7
    const int l   = tid & 63;
    const int wr  = w >> 2;       // 0..1  (64-row slice within quadrant)
    const int wc  = w & 3;        // 0..3  (32-col slice within quadrant)

    // bijective XCD swizzle (256 blocks, 8 XCDs, 32 contiguous per XCD)
    const int wg  = blockIdx.y * 16 + blockIdx.x;
    const int idx = ((wg & 7) << 5) | (wg >> 3);
    const int bm0 = (idx >> 4) * 256;   // batch rows
    const int bn0 = (idx & 15) * 256;   // N cols

    f32x4 acc[2][4][2][2];
#pragma unroll
    for (int a = 0; a < 2; ++a)
#pragma unroll
        for (int b = 0; b < 4; ++b)
#pragma unroll
            for (int c = 0; c < 2; ++c)
#pragma unroll
                for (int d = 0; d < 2; ++d) acc[a][b][c][d] = (f32x4)0.0f;

    // ---- prologue: stage K-tile 0 fully into buf0 ----
    stage_half(Xb, bm0,       0, As0,        w, l);
    stage_half(Wb, bn0,       0, Bs0,        w, l);
    stage_half(Xb, bm0 + 128, 0, As0 + 8192, w, l);
    stage_half(Wb, bn0 + 128, 0, Bs0 + 8192, w, l);
    // (tile-head of the first ktile performs the vmcnt(0)+barrier)

    // ---- main loop: 2 K-tiles per iteration ----
#pragma unroll 1
    for (int kt = 0; kt < M_DIM; kt += 128) {
        ktile(As0, Bs0, As1, Bs1, Xb, Wb, bm0, bn0, kt + 64, true,
              wr, wc, w, l, acc);
        ktile(As1, Bs1, As0, Bs0, Xb, Wb, bm0, bn0, kt + 128,
              kt + 128 < M_DIM, wr, wc, w, l, acc);
    }

    // ---- epilogue: D elem r of acc -> row = (l>>4)*4+r, col = l&15 ----
    const int l15 = l & 15;
    const int lg  = l >> 4;
#pragma unroll
    for (int nb = 0; nb < 2; ++nb)
#pragma unroll
        for (int nf = 0; nf < 2; ++nf) {
            const int col = bn0 + nb * 128 + wc * 32 + nf * 16 + l15;
            const float bv = bias[col];
#pragma unroll
            for (int ma = 0; ma < 2; ++ma)
#pragma unroll
                for (int mf = 0; mf < 4; ++mf) {
                    const int row0 = bm0 + ma * 128 + wr * 64 + mf * 16 + lg * 4;
#pragma unroll
                    for (int r = 0; r < 4; ++r)
                        out[(size_t)(row0 + r) * N_DIM + col] =
                            acc[ma][mf][nb][nf][r] + bv;
                }
        }
}

// ---------------------------------------------------------------------------

extern "C" void kernel_launch(void* const* d_in, const int* in_sizes, int n_in,
                              void* d_out, int out_size, void* d_ws, size_t ws_size,
                              hipStream_t stream) {
    const float* x       = (const float*)d_in[0];
    const float* wval    = (const float*)d_in[1];
    const float* bias    = (const float*)d_in[2];
    const int*   cols    = (const int*)d_in[4];
    float* out = (float*)d_out;

    // workspace: Wb [N*M bf16] (32 MiB) | Xb [B*M bf16] (32 MiB)
    unsigned short* Wb = (unsigned short*)d_ws;
    unsigned short* Xb = Wb + (size_t)N_DIM * M_DIM;

    // merged prologue: 4096 densify blocks + 8192 cvt blocks
    prep<<<dim3(N_DIM + (B_DIM * M_DIM) / 8 / 256), dim3(256), 0, stream>>>(
        wval, cols, Wb, (const float4*)x, (uint4*)Xb);
    gemm_bt_bias<<<dim3(N_DIM / 256, B_DIM / 256), dim3(512), 0, stream>>>(
        Xb, Wb, bias, out);
}

// Round 6
// 267.005 us; speedup vs baseline: 1.2351x; 1.2351x over previous
//
#include <hip/hip_runtime.h>
#include <hip/hip_bf16.h>
#include <stdint.h>

// ---------------------------------------------------------------------------
// SparseLinear: y[B,N] = x[B,M] @ W^T + bias, W given as CSR.
// R9: R8's 1-barrier-per-K-tile structure, register-pressure-fixed.
//   R8 post-mortem: WRITE_SIZE 70->137 MB = scratch spills. With no fences
//   the scheduler hoisted all 24 ds_reads to the tile top -> 6 frag sets
//   (96 VGPR) + acc (128) + staging addresses live at once -> spill in the
//   hot loop. Fix, by construction:
//   - NO read-ahead: each step reads its fragments right before its MFMA
//     cluster; 8 free-running waves hide read latency in each other's MFMA
//     issue (MFMA pipe needs 2483 cyc/tile; waves supply 8x312 cyc issue).
//   - sched_barrier(0) at each step boundary = anti-hoist fence. B-set live
//     ranges don't overlap (bk0 dies at MFMA1, bk1 read at step2) -> peak
//     ~210 VGPR < 256 budget (8-wave block REQUIRES 2 waves/SIMD).
//   Tile: vmcnt(0) [retires stages issued a FULL tile ago -- ~0 stall] ->
//   s_barrier [publish; WAR-gate] -> stage 8 loads (tile t+1) ->
//   {read step-s frags; MFMA step-s; sched_barrier(0)} x4.
//   Steps (MA,KS): (0,k0),(1,k0),(0,k1),(1,k1); per-acc order k0-then-k1
//   -> bit-identical results. Hazard proofs as R8 (unchanged).
// ---------------------------------------------------------------------------

#define B_DIM 4096
#define M_DIM 4096
#define N_DIM 4096
#define NNZ_ROW 819

typedef __attribute__((ext_vector_type(8))) __bf16 bf16x8;
typedef __attribute__((ext_vector_type(4))) float f32x4;

__device__ __forceinline__ unsigned short f32_to_bf16(float f) {
    union { float f; unsigned int u; } v;
    v.f = f;
    unsigned int r = v.u + 0x7FFFu + ((v.u >> 16) & 1u);  // RNE
    return (unsigned short)(r >> 16);
}

__device__ __forceinline__ void load_lds16(const void* g, void* l) {
    __builtin_amdgcn_global_load_lds(
        (const __attribute__((address_space(1))) void*)g,
        (__attribute__((address_space(3))) void*)l,
        16, 0, 0);
}

// ---- merged prologue: densify W rows (blocks 0..4095) + X fp32->bf16
//      (blocks 4096..12287, 8 floats/thread, exact grid) --------------------
__global__ __launch_bounds__(256) void prep(
    const float* __restrict__ wval,
    const int* __restrict__ cols,
    unsigned short* __restrict__ wb,
    const float4* __restrict__ x,
    uint4* __restrict__ xb) {
    const int tid = threadIdx.x;
    if (blockIdx.x >= N_DIM) {
        const int i = (blockIdx.x - N_DIM) * 256 + tid;   // 0 .. 2M-1, exact
        const float4 a = x[2 * i];
        const float4 b = x[2 * i + 1];
        union { ushort ush[8]; uint4 u4; } o;
        o.ush[0] = f32_to_bf16(a.x); o.ush[1] = f32_to_bf16(a.y);
        o.ush[2] = f32_to_bf16(a.z); o.ush[3] = f32_to_bf16(a.w);
        o.ush[4] = f32_to_bf16(b.x); o.ush[5] = f32_to_bf16(b.y);
        o.ush[6] = f32_to_bf16(b.z); o.ush[7] = f32_to_bf16(b.w);
        xb[i] = o.u4;
        return;
    }
    __shared__ __attribute__((aligned(16))) unsigned short row_s[M_DIM];  // 8 KB
    const int row = blockIdx.x;
    uint4* rs4 = (uint4*)row_s;
    rs4[tid]       = make_uint4(0u, 0u, 0u, 0u);
    rs4[tid + 256] = make_uint4(0u, 0u, 0u, 0u);
    __syncthreads();
    const size_t base = (size_t)row * NNZ_ROW;
    for (int j = tid; j < NNZ_ROW; j += 256) {
        const int c = cols[base + j];
        row_s[c] = f32_to_bf16(wval[base + j]);
    }
    __syncthreads();
    uint4* dst = (uint4*)(wb + (size_t)row * M_DIM);
    dst[tid]       = rs4[tid];
    dst[tid + 256] = rs4[tid + 256];
}

// ---------------------------------------------------------------------------
// Stage one 128-row half-tile (128 rows x 64 k, bf16) for K-offset kt.
// LDS dest LINEAR: wave w covers segments {2w,2w+1}; lane's 16B slot is
// (row r = seg*8 + (l>>3), chunk' = l&7); LDS(r,c') holds global chunk
// c' ^ (r&7) = (l&7) ^ (l>>3).
// ---------------------------------------------------------------------------
__device__ __forceinline__ void stage_half(
    const unsigned short* __restrict__ src,
    int grow0, int kt, unsigned short* dst, int w, int l) {
#pragma unroll
    for (int j = 0; j < 2; ++j) {
        const int seg = w * 2 + j;
        const int r   = seg * 8 + (l >> 3);
        const int cg  = (l >> 3) ^ (l & 7);
        load_lds16(src + (size_t)(grow0 + r) * M_DIM + kt + cg * 8,
                   dst + seg * 512);
    }
}

#define MFMA_STEP(MA, ASET, BSET)                                              \
    __builtin_amdgcn_s_setprio(1);                                             \
    _Pragma("unroll")                                                          \
    for (int mf = 0; mf < 4; ++mf)                                             \
        _Pragma("unroll")                                                      \
        for (int nb = 0; nb < 2; ++nb)                                         \
            _Pragma("unroll")                                                  \
            for (int nf = 0; nf < 2; ++nf)                                     \
                acc[MA][mf][nb][nf] =                                          \
                    __builtin_amdgcn_mfma_f32_16x16x32_bf16(                   \
                        ASET[mf], BSET[nb][nf], acc[MA][mf][nb][nf], 0, 0, 0); \
    __builtin_amdgcn_s_setprio(0);

// ---------------------------------------------------------------------------
// One K-tile: 4 (MA,KS) steps, single head barrier, free-running waves.
// Fragment addressing (proven R7): row = quad + mf*16 + l15, chunk
// c = KS*4 + (l>>4), stored at chunk' = c ^ (row&7) = c ^ (l&7).
// ---------------------------------------------------------------------------
__device__ __forceinline__ void ktile(
    const unsigned short* As_c, const unsigned short* Bs_c,
    unsigned short* As_n, unsigned short* Bs_n,
    const unsigned short* __restrict__ Xb, const unsigned short* __restrict__ Wb,
    int bm0, int bn0, int knext, bool do_stage,
    int wr, int wc, int w, int l, f32x4 (&acc)[2][4][2][2])
{
    __builtin_amdgcn_s_waitcnt(0x0F70);   // vmcnt(0): retires stages issued a
                                          // full tile ago (~0 residual stall)
    __builtin_amdgcn_s_barrier();         // publish cur; WAR-gate nxt staging

    const int l15 = l & 15;
    const int lg  = l >> 4;
    const int lx  = l & 7;
    const int ck0 = (lg ^ lx) << 3;          // KS=0 ushort offset within row
    const int ck1 = ((4 + lg) ^ lx) << 3;    // KS=1

    const unsigned short* A0 = As_c + (wr * 64 + l15) * 64;          // MA=0
    const unsigned short* A1 = A0 + 128 * 64;                        // MA=1
    const unsigned short* B0 = Bs_c + (wc * 32 + l15) * 64;          // nb=0
    const unsigned short* B1 = B0 + 128 * 64;                        // nb=1

    // stage next tile first: maximum slack before its retiring vmcnt(0)
    if (do_stage) {
        stage_half(Xb, bm0,       knext, As_n,        w, l);
        stage_half(Wb, bn0,       knext, Bs_n,        w, l);
        stage_half(Xb, bm0 + 128, knext, As_n + 8192, w, l);
        stage_half(Wb, bn0 + 128, knext, Bs_n + 8192, w, l);
    }
    __builtin_amdgcn_sched_barrier(0);

    // ---- step 0: (MA=0, k0) ----
    {
        bf16x8 a0k0[4], bk0[2][2];
#pragma unroll
        for (int mf = 0; mf < 4; ++mf)
            a0k0[mf] = *(const bf16x8*)(A0 + mf * 1024 + ck0);
#pragma unroll
        for (int nf = 0; nf < 2; ++nf) {
            bk0[0][nf] = *(const bf16x8*)(B0 + nf * 1024 + ck0);
            bk0[1][nf] = *(const bf16x8*)(B1 + nf * 1024 + ck0);
        }
        MFMA_STEP(0, a0k0, bk0)
        __builtin_amdgcn_sched_barrier(0);

        // ---- step 1: (MA=1, k0) -- reuses bk0 ----
        bf16x8 a1k0[4];
#pragma unroll
        for (int mf = 0; mf < 4; ++mf)
            a1k0[mf] = *(const bf16x8*)(A1 + mf * 1024 + ck0);
        MFMA_STEP(1, a1k0, bk0)
    }
    __builtin_amdgcn_sched_barrier(0);

    // ---- step 2: (MA=0, k1) ----
    {
        bf16x8 a0k1[4], bk1[2][2];
#pragma unroll
        for (int mf = 0; mf < 4; ++mf)
            a0k1[mf] = *(const bf16x8*)(A0 + mf * 1024 + ck1);
#pragma unroll
        for (int nf = 0; nf < 2; ++nf) {
            bk1[0][nf] = *(const bf16x8*)(B0 + nf * 1024 + ck1);
            bk1[1][nf] = *(const bf16x8*)(B1 + nf * 1024 + ck1);
        }
        MFMA_STEP(0, a0k1, bk1)
        __builtin_amdgcn_sched_barrier(0);

        // ---- step 3: (MA=1, k1) -- reuses bk1 ----
        bf16x8 a1k1[4];
#pragma unroll
        for (int mf = 0; mf < 4; ++mf)
            a1k1[mf] = *(const bf16x8*)(A1 + mf * 1024 + ck1);
        MFMA_STEP(1, a1k1, bk1)
    }
    __builtin_amdgcn_sched_barrier(0);
}

// ---- main GEMM: C[b,n] = sum_k Xb[b,k]*Wb[n,k] + bias[n] -------------------
__global__ __launch_bounds__(512, 2) void gemm_bt_bias(
    const unsigned short* __restrict__ Xb,   // [B][M] bf16 bits
    const unsigned short* __restrict__ Wb,   // [N][M] bf16 bits
    const float* __restrict__ bias,          // [N]
    float* __restrict__ out)                 // [B][N]
{
    __shared__ __attribute__((aligned(16))) unsigned short As0[16384];
    __shared__ __attribute__((aligned(16))) unsigned short Bs0[16384];
    __shared__ __attribute__((aligned(16))) unsigned short As1[16384];
    __shared__ __attribute__((aligned(16))) unsigned short Bs1[16384];

    const int tid = threadIdx.x;
    const int w   = tid >> 6;     // wave 0..7
    const int l   = tid & 63;
    const int wr  = w >> 2;       // 0..1  (64-row slice within quadrant)
    const int wc  = w & 3;        // 0..3  (32-col slice within quadrant)

    // bijective XCD swizzle (256 blocks, 8 XCDs, 32 contiguous per XCD)
    const int wg  = blockIdx.y * 16 + blockIdx.x;
    const int idx = ((wg & 7) << 5) | (wg >> 3);
    const int bm0 = (idx >> 4) * 256;   // batch rows
    const int bn0 = (idx & 15) * 256;   // N cols

    f32x4 acc[2][4][2][2];
#pragma unroll
    for (int a = 0; a < 2; ++a)
#pragma unroll
        for (int b = 0; b < 4; ++b)
#pragma unroll
            for (int c = 0; c < 2; ++c)
#pragma unroll
                for (int d = 0; d < 2; ++d) acc[a][b][c][d] = (f32x4)0.0f;

    // ---- prologue: stage K-tile 0 fully into buf0 ----
    stage_half(Xb, bm0,       0, As0,        w, l);
    stage_half(Wb, bn0,       0, Bs0,        w, l);
    stage_half(Xb, bm0 + 128, 0, As0 + 8192, w, l);
    stage_half(Wb, bn0 + 128, 0, Bs0 + 8192, w, l);
    // (tile-head of the first ktile performs the vmcnt(0)+barrier)

    // ---- main loop: 2 K-tiles per iteration ----
#pragma unroll 1
    for (int kt = 0; kt < M_DIM; kt += 128) {
        ktile(As0, Bs0, As1, Bs1, Xb, Wb, bm0, bn0, kt + 64, true,
              wr, wc, w, l, acc);
        ktile(As1, Bs1, As0, Bs0, Xb, Wb, bm0, bn0, kt + 128,
              kt + 128 < M_DIM, wr, wc, w, l, acc);
    }

    // ---- epilogue: D elem r of acc -> row = (l>>4)*4+r, col = l&15 ----
    const int l15 = l & 15;
    const int lg  = l >> 4;
#pragma unroll
    for (int nb = 0; nb < 2; ++nb)
#pragma unroll
        for (int nf = 0; nf < 2; ++nf) {
            const int col = bn0 + nb * 128 + wc * 32 + nf * 16 + l15;
            const float bv = bias[col];
#pragma unroll
            for (int ma = 0; ma < 2; ++ma)
#pragma unroll
                for (int mf = 0; mf < 4; ++mf) {
                    const int row0 = bm0 + ma * 128 + wr * 64 + mf * 16 + lg * 4;
#pragma unroll
                    for (int r = 0; r < 4; ++r)
                        out[(size_t)(row0 + r) * N_DIM + col] =
                            acc[ma][mf][nb][nf][r] + bv;
                }
        }
}

// ---------------------------------------------------------------------------

extern "C" void kernel_launch(void* const* d_in, const int* in_sizes, int n_in,
                              void* d_out, int out_size, void* d_ws, size_t ws_size,
                              hipStream_t stream) {
    const float* x       = (const float*)d_in[0];
    const float* wval    = (const float*)d_in[1];
    const float* bias    = (const float*)d_in[2];
    const int*   cols    = (const int*)d_in[4];
    float* out = (float*)d_out;

    // workspace: Wb [N*M bf16] (32 MiB) | Xb [B*M bf16] (32 MiB)
    unsigned short* Wb = (unsigned short*)d_ws;
    unsigned short* Xb = Wb + (size_t)N_DIM * M_DIM;

    // merged prologue: 4096 densify blocks + 8192 cvt blocks
    prep<<<dim3(N_DIM + (B_DIM * M_DIM) / 8 / 256), dim3(256), 0, stream>>>(
        wval, cols, Wb, (const float4*)x, (uint4*)Xb);
    gemm_bt_bias<<<dim3(N_DIM / 256, B_DIM / 256), dim3(512), 0, stream>>>(
        Xb, Wb, bias, out);
}